// Round 2
// baseline (1188.540 us; speedup 1.0000x reference)
//
#include <hip/hip_runtime.h>
#include <hip/hip_bf16.h>

typedef __bf16 bf16_t;
typedef __bf16 bf16x8 __attribute__((ext_vector_type(8)));
typedef float f32x4 __attribute__((ext_vector_type(4)));

#define B_DIM 8
#define LQ 1024
#define LK 1024
#define DD 512
#define NH 8

static __device__ __forceinline__ f32x4 mfma_bf16(bf16x8 a, bf16x8 b, f32x4 c) {
  return __builtin_amdgcn_mfma_f32_16x16x32_bf16(a, b, c, 0, 0, 0);
}

// Stage 16 contiguous elements (one thread's share of a 32-wide k-slice) into LDS
// as bf16, converting from fp32 if needed.
static __device__ __forceinline__ void stage16(const float* __restrict__ g, bf16_t* l) {
  const float4* s = (const float4*)g;
  const float4 f0 = s[0], f1 = s[1], f2 = s[2], f3 = s[3];
  bf16x8 v0 = {(bf16_t)f0.x, (bf16_t)f0.y, (bf16_t)f0.z, (bf16_t)f0.w,
               (bf16_t)f1.x, (bf16_t)f1.y, (bf16_t)f1.z, (bf16_t)f1.w};
  bf16x8 v1 = {(bf16_t)f2.x, (bf16_t)f2.y, (bf16_t)f2.z, (bf16_t)f2.w,
               (bf16_t)f3.x, (bf16_t)f3.y, (bf16_t)f3.z, (bf16_t)f3.w};
  *(bf16x8*)l = v0;
  *(bf16x8*)(l + 8) = v1;
}
static __device__ __forceinline__ void stage16(const bf16_t* __restrict__ g, bf16_t* l) {
  const uint4* s = (const uint4*)g;
  ((uint4*)l)[0] = s[0];
  ((uint4*)l)[1] = s[1];
}

// ---------------- generic NT GEMM: C[m,n] = sum_k A[m,k]*B[n,k] + bias ----------------
// A: [M,K] row-major (lda=K), B: [N,K] row-major (ldb=K); fp32 or bf16, converted
// to bf16 during LDS staging. blockIdx.z = local_batch*NH + h.
// bias_mode: 0 none, 1 per-col, 2 per-row.
template <typename AT, typename BT, typename CT>
__global__ __launch_bounds__(256, 2) void gemm_nt(
    const AT* __restrict__ A, const BT* __restrict__ B,
    const float* __restrict__ bias, CT* __restrict__ C,
    int M, int N, int K, int ldc,
    long long a_bs, long long a_hs, long long b_bs, long long b_hs,
    long long c_bs, long long c_hs, long long bias_hs, int bias_mode)
{
  const int z = blockIdx.z, bb = z >> 3, hh = z & 7;
  A += (size_t)bb * a_bs + (size_t)hh * a_hs;
  B += (size_t)bb * b_bs + (size_t)hh * b_hs;
  C += (size_t)bb * c_bs + (size_t)hh * c_hs;
  const float* bias_p = bias + (size_t)hh * bias_hs;

  const int m0 = blockIdx.x * 128, n0 = blockIdx.y * 128;
  const int tid = threadIdx.x;
  const int wave = tid >> 6, lane = tid & 63;
  const int l15 = lane & 15, quad = lane >> 4;
  const int wm = (wave & 1) * 64, wn = (wave >> 1) * 64;

  __shared__ __align__(16) bf16_t As[128][40];  // +8 pad: 2-way conflicts only
  __shared__ __align__(16) bf16_t Bs[128][40];

  f32x4 acc[4][4];
#pragma unroll
  for (int i = 0; i < 4; ++i)
#pragma unroll
    for (int j = 0; j < 4; ++j) acc[i][j] = (f32x4){0.f, 0.f, 0.f, 0.f};

  const int srow = tid >> 1, scol = (tid & 1) * 16;
  const AT* Ag = A + (size_t)(m0 + srow) * K + scol;
  const BT* Bg = B + (size_t)(n0 + srow) * K + scol;

  for (int k0 = 0; k0 < K; k0 += 32) {
    __syncthreads();
    stage16(Ag + k0, &As[srow][scol]);
    stage16(Bg + k0, &Bs[srow][scol]);
    __syncthreads();
    bf16x8 af[4], bfr[4];
#pragma unroll
    for (int i = 0; i < 4; ++i) af[i] = *(const bf16x8*)&As[wm + i * 16 + l15][quad * 8];
#pragma unroll
    for (int j = 0; j < 4; ++j) bfr[j] = *(const bf16x8*)&Bs[wn + j * 16 + l15][quad * 8];
#pragma unroll
    for (int i = 0; i < 4; ++i)
#pragma unroll
      for (int j = 0; j < 4; ++j)
        acc[i][j] = mfma_bf16(af[i], bfr[j], acc[i][j]);
  }

#pragma unroll
  for (int i = 0; i < 4; ++i)
#pragma unroll
    for (int j = 0; j < 4; ++j)
#pragma unroll
      for (int r = 0; r < 4; ++r) {
        const int row = m0 + wm + i * 16 + quad * 4 + r;
        const int col = n0 + wn + j * 16 + l15;
        float v = acc[i][j][r];
        if (bias_mode == 1) v += bias_p[col];
        else if (bias_mode == 2) v += bias_p[row];
        C[(size_t)row * ldc + col] = (CT)v;
      }
}

// ---------------- flash attention ----------------
// grid (LQ/64, nb*NH), 256 threads. Wave w handles 16 q-rows.
// Q,K: [nb,NH,L,DD] bf16. Vt: [nb,NH,DD,LK] bf16. mask: [nb,LQ,LK] int.
// ctx out: [nb,LQ,NH*DD] bf16. All pointers pre-offset to the batch chunk.
__global__ __launch_bounds__(256, 1) void flash_attn(
    const bf16_t* __restrict__ Q, const bf16_t* __restrict__ K,
    const bf16_t* __restrict__ Vt, const int* __restrict__ mask,
    bf16_t* __restrict__ ctx)
{
  const float scale = 0.04419417382415922f;  // 1/sqrt(512)
  const int qt = blockIdx.x, bh = blockIdx.y;
  const int bb = bh >> 3, hh = bh & 7;
  const int tid = threadIdx.x, wave = tid >> 6, lane = tid & 63;
  const int l15 = lane & 15, quad = lane >> 4;

  __shared__ __align__(16) bf16_t Ks[32][520];      // 32 keys x 512 d (+8 pad)
  __shared__ __align__(16) bf16_t Vs[512][40];      // 512 d x 32 keys (+8 pad)
  __shared__ __align__(16) bf16_t Ps[4][16][40];    // per-wave P transpose buffer

  const bf16_t* Qb = Q + (size_t)bh * LQ * DD;
  const bf16_t* Kb = K + (size_t)bh * LK * DD;
  const bf16_t* Vb = Vt + (size_t)bh * DD * LK;
  const int* mb = mask + (size_t)bb * LQ * LK;

  const int q0 = qt * 64 + wave * 16;

  // Q fragments in registers: 16 rows x 512 cols (A-layout per 32-chunk)
  bf16x8 qf[16];
  {
    const bf16_t* qp = Qb + (size_t)(q0 + l15) * DD + quad * 8;
#pragma unroll
    for (int kc = 0; kc < 16; ++kc) qf[kc] = *(const bf16x8*)(qp + kc * 32);
  }

  f32x4 acc[32];
#pragma unroll
  for (int i = 0; i < 32; ++i) acc[i] = (f32x4){0.f, 0.f, 0.f, 0.f};
  float mrow[4] = {-3e38f, -3e38f, -3e38f, -3e38f};
  float lrow[4] = {0.f, 0.f, 0.f, 0.f};

  for (int kt = 0; kt < LK / 32; ++kt) {
    const int k0 = kt * 32;
    __syncthreads();  // previous iteration's readers are done
    {   // stage K tile: 32 rows x 512 d ; 128 B per thread
      const int row = tid >> 3, c0 = (tid & 7) * 64;
      const uint4* s = (const uint4*)(Kb + (size_t)(k0 + row) * DD + c0);
      uint4* d = (uint4*)&Ks[row][c0];
#pragma unroll
      for (int i = 0; i < 8; ++i) d[i] = s[i];
    }
    {   // stage Vt tile: 512 d x 32 keys ; 4x32 B per thread
      const int rr = tid >> 1, c0 = (tid & 1) * 16;
#pragma unroll
      for (int p = 0; p < 4; ++p) {
        const int dd = p * 128 + rr;
        const uint4* s = (const uint4*)(Vb + (size_t)dd * LK + k0 + c0);
        uint4* d = (uint4*)&Vs[dd][c0];
        d[0] = s[0]; d[1] = s[1];
      }
    }
    __syncthreads();

    // S (16q x 32k) = Q . K^T
    f32x4 s0 = {0.f, 0.f, 0.f, 0.f}, s1 = {0.f, 0.f, 0.f, 0.f};
#pragma unroll
    for (int kc = 0; kc < 16; ++kc) {
      bf16x8 kf0 = *(const bf16x8*)&Ks[l15][kc * 32 + quad * 8];
      bf16x8 kf1 = *(const bf16x8*)&Ks[16 + l15][kc * 32 + quad * 8];
      s0 = mfma_bf16(qf[kc], kf0, s0);
      s1 = mfma_bf16(qf[kc], kf1, s1);
    }

    // mask + online softmax (q-row = quad*4+r; 2x16 key cols live in the quad's lanes)
    float alpha_r[4];
#pragma unroll
    for (int r = 0; r < 4; ++r) {
      const int qrow = q0 + quad * 4 + r;
      const int* mp = mb + (size_t)qrow * LK + k0;
      float v0 = s0[r] * scale;
      float v1 = s1[r] * scale;
      if (mp[l15] == 0) v0 = -3e38f;
      if (mp[16 + l15] == 0) v1 = -3e38f;
      float mx = fmaxf(v0, v1);
      mx = fmaxf(mx, __shfl_xor(mx, 1));
      mx = fmaxf(mx, __shfl_xor(mx, 2));
      mx = fmaxf(mx, __shfl_xor(mx, 4));
      mx = fmaxf(mx, __shfl_xor(mx, 8));
      const float mnew = fmaxf(mrow[r], mx);
      const float alpha = __expf(mrow[r] - mnew);
      float p0 = __expf(v0 - mnew);
      float p1 = __expf(v1 - mnew);
      if (mnew < -1e37f) { p0 = 0.f; p1 = 0.f; }  // fully-masked prefix guard
      float ps = p0 + p1;
      ps += __shfl_xor(ps, 1);
      ps += __shfl_xor(ps, 2);
      ps += __shfl_xor(ps, 4);
      ps += __shfl_xor(ps, 8);
      lrow[r] = lrow[r] * alpha + ps;
      mrow[r] = mnew;
      alpha_r[r] = alpha;
      Ps[wave][quad * 4 + r][l15] = (bf16_t)p0;
      Ps[wave][quad * 4 + r][16 + l15] = (bf16_t)p1;
    }
    // Ps is wave-private: in-wave LDS write->read needs no barrier (lgkmcnt only).

    // ctx += P . V  (rescale by alpha first)
    bf16x8 pf = *(const bf16x8*)&Ps[wave][l15][quad * 8];
#pragma unroll
    for (int ni = 0; ni < 32; ++ni) {
      f32x4 a = acc[ni];
      a[0] *= alpha_r[0]; a[1] *= alpha_r[1]; a[2] *= alpha_r[2]; a[3] *= alpha_r[3];
      bf16x8 vf = *(const bf16x8*)&Vs[ni * 16 + l15][quad * 8];
      acc[ni] = mfma_bf16(pf, vf, a);
    }
  }

  float inv[4];
#pragma unroll
  for (int r = 0; r < 4; ++r) inv[r] = 1.f / lrow[r];
  bf16_t* cb = ctx + ((size_t)bb * LQ) * (NH * DD) + (size_t)hh * DD;
#pragma unroll
  for (int ni = 0; ni < 32; ++ni)
#pragma unroll
    for (int r = 0; r < 4; ++r) {
      const int q = q0 + quad * 4 + r;
      const int d = ni * 16 + l15;
      cb[(size_t)q * (NH * DD) + d] = (bf16_t)(acc[ni][r] * inv[r]);
    }
}

// ---------------- host launcher ----------------
extern "C" void kernel_launch(void* const* d_in, const int* in_sizes, int n_in,
                              void* d_out, int out_size, void* d_ws, size_t ws_size,
                              hipStream_t stream) {
  const float* x      = (const float*)d_in[0];
  const float* states = (const float*)d_in[1];
  const int*   mask   = (const int*)d_in[2];
  const float* Wq     = (const float*)d_in[3];
  const float* bq     = (const float*)d_in[4];
  const float* Wk     = (const float*)d_in[5];
  const float* bk     = (const float*)d_in[6];
  const float* Wv     = (const float*)d_in[7];
  const float* bv     = (const float*)d_in[8];
  const float* Wp     = (const float*)d_in[9];
  const float* bp     = (const float*)d_in[10];
  float* out = (float*)d_out;

  // Workspace layout (160 MB total):
  //   ctx : [B, LQ, NH*DD] bf16, 64 MB, offset 0
  //   Qc  : [4, NH, LQ, DD] bf16, 32 MB  (per 4-batch chunk)
  //   Kc  : [4, NH, LK, DD] bf16, 32 MB
  //   Vtc : [4, NH, DD, LK] bf16, 32 MB
  char* ws = (char*)d_ws;
  bf16_t* ctxb = (bf16_t*)(ws + 0);
  bf16_t* Qc   = (bf16_t*)(ws + 67108864);
  bf16_t* Kc   = (bf16_t*)(ws + 100663296);
  bf16_t* Vtc  = (bf16_t*)(ws + 134217728);

  const long long xbs = (long long)LQ * DD;      // fp32 x/states batch stride
  const long long whs = (long long)DD * DD;      // per-head weight stride

  for (int c = 0; c < 2; ++c) {
    const float* xc = x + (size_t)c * 4 * LQ * DD;
    const float* sc = states + (size_t)c * 4 * LK * DD;
    const int* mc = mask + (size_t)c * 4 * LQ * LK;
    bf16_t* ctxc = ctxb + (size_t)c * 4 * LQ * (NH * DD);

    // Q = x @ Wq^T + bq : per (b,h) M=1024,N=512,K=512 -> Qc[b,h,q,d]
    gemm_nt<float, float, bf16_t><<<dim3(8, 4, 32), 256, 0, stream>>>(
        xc, Wq, bq, Qc, LQ, DD, DD, DD,
        xbs, 0LL, 0LL, whs,
        (long long)NH * LQ * DD, (long long)LQ * DD, DD, 1);
    // K = states @ Wk^T + bk
    gemm_nt<float, float, bf16_t><<<dim3(8, 4, 32), 256, 0, stream>>>(
        sc, Wk, bk, Kc, LK, DD, DD, DD,
        xbs, 0LL, 0LL, whs,
        (long long)NH * LK * DD, (long long)LK * DD, DD, 1);
    // Vt[b,h,d,k] = Wv[h,d,:] . states[b,k,:] + bv[h,d]  (M=512 d, N=1024 k)
    gemm_nt<float, float, bf16_t><<<dim3(4, 8, 32), 256, 0, stream>>>(
        Wv, sc, bv, Vtc, DD, LK, DD, LK,
        0LL, whs, xbs, 0LL,
        (long long)NH * DD * LK, (long long)DD * LK, DD, 2);

    flash_attn<<<dim3(LQ / 64, 32), 256, 0, stream>>>(Qc, Kc, Vtc, mc, ctxc);
  }

  // out = ctx @ Wp^T + bp : M=8192, N=512, K=4096
  gemm_nt<bf16_t, float, float><<<dim3(64, 4, 1), 256, 0, stream>>>(
      ctxb, Wp, bp, out, B_DIM * LQ, DD, NH * DD, DD,
      0LL, 0LL, 0LL, 0LL, 0LL, 0LL, 0LL, 1);
}